// Round 1
// baseline (1463.815 us; speedup 1.0000x reference)
//
#include <hip/hip_runtime.h>

#define N_NODES 50000
#define N_GENES 256
#define N_EDGES 800000
#define NUM_ITERS 10

// ---------------- CSR build (once per launch; cheap vs 10 SpMM passes) ----

__global__ void hist_kernel(const int* __restrict__ dst, int* __restrict__ counts) {
    int e = blockIdx.x * blockDim.x + threadIdx.x;
    if (e < N_EDGES) atomicAdd(&counts[dst[e]], 1);
}

// Single-block exclusive scan over N_NODES counts -> offsets[N_NODES+1], and
// initializes cursor[] = offsets[] for the scatter pass.
__global__ void exscan_kernel(const int* __restrict__ counts,
                              int* __restrict__ offsets,
                              int* __restrict__ cursor) {
    const int n = N_NODES;
    __shared__ int buf[1024];
    __shared__ int carry_s;
    if (threadIdx.x == 0) carry_s = 0;
    __syncthreads();
    for (int base = 0; base < n; base += 1024) {
        int i = base + threadIdx.x;
        int v = (i < n) ? counts[i] : 0;
        buf[threadIdx.x] = v;
        __syncthreads();
        // Hillis-Steele inclusive scan over 1024 elements
        for (int off = 1; off < 1024; off <<= 1) {
            int t = (threadIdx.x >= off) ? buf[threadIdx.x - off] : 0;
            __syncthreads();
            buf[threadIdx.x] += t;
            __syncthreads();
        }
        int incl = buf[threadIdx.x];
        int carry = carry_s;
        if (i < n) {
            int ex = carry + incl - v;
            offsets[i] = ex;
            cursor[i]  = ex;
        }
        __syncthreads();
        if (threadIdx.x == 1023) carry_s = carry + incl;  // incl == chunk total here
        __syncthreads();
    }
    if (threadIdx.x == 0) offsets[n] = carry_s;
}

__global__ void scatter_kernel(const int* __restrict__ dst,
                               const int* __restrict__ src,
                               const float* __restrict__ w,
                               int* __restrict__ cursor,
                               int* __restrict__ ssrc,
                               float* __restrict__ sw) {
    int e = blockIdx.x * blockDim.x + threadIdx.x;
    if (e < N_EDGES) {
        int d = dst[e];
        int p = atomicAdd(&cursor[d], 1);
        ssrc[p] = src[e];
        sw[p]   = w[e];
    }
}

// ---------------- Propagation: one wave (64 lanes) per destination node ---
// acc[256 genes] = 64 lanes x float4. Gather h[src] rows (contiguous 1KB,
// fully coalesced), fma by edge weight, then fused clamp: known entries
// (orig != 0) are reset to orig on write. No atomics, no zero-init.

__global__ __launch_bounds__(256) void prop_kernel(
        const float* __restrict__ h,
        const float* __restrict__ orig,
        const int* __restrict__ offsets,
        const int* __restrict__ ssrc,
        const float* __restrict__ sw,
        float* __restrict__ out) {
    int node = blockIdx.x * (blockDim.x >> 6) + (threadIdx.x >> 6);
    if (node >= N_NODES) return;
    int lane4 = (threadIdx.x & 63) << 2;  // gene offset: lane*4

    int beg = offsets[node];
    int end = offsets[node + 1];

    float4 acc = make_float4(0.f, 0.f, 0.f, 0.f);
    int e = beg;
    // 2-deep unroll for memory-level parallelism on the gather
    for (; e + 1 < end; e += 2) {
        int   s0 = ssrc[e],   s1 = ssrc[e + 1];
        float w0 = sw[e],     w1 = sw[e + 1];
        float4 r0 = *reinterpret_cast<const float4*>(&h[(size_t)s0 * N_GENES + lane4]);
        float4 r1 = *reinterpret_cast<const float4*>(&h[(size_t)s1 * N_GENES + lane4]);
        acc.x += w0 * r0.x + w1 * r1.x;
        acc.y += w0 * r0.y + w1 * r1.y;
        acc.z += w0 * r0.z + w1 * r1.z;
        acc.w += w0 * r0.w + w1 * r1.w;
    }
    if (e < end) {
        int   s0 = ssrc[e];
        float w0 = sw[e];
        float4 r0 = *reinterpret_cast<const float4*>(&h[(size_t)s0 * N_GENES + lane4]);
        acc.x += w0 * r0.x;
        acc.y += w0 * r0.y;
        acc.z += w0 * r0.z;
        acc.w += w0 * r0.w;
    }

    size_t idx = (size_t)node * N_GENES + lane4;
    float4 o = *reinterpret_cast<const float4*>(&orig[idx]);
    float4 r;
    r.x = (o.x != 0.f) ? o.x : acc.x;
    r.y = (o.y != 0.f) ? o.y : acc.y;
    r.z = (o.z != 0.f) ? o.z : acc.z;
    r.w = (o.w != 0.f) ? o.w : acc.w;
    *reinterpret_cast<float4*>(&out[idx]) = r;
}

// --------------------------------------------------------------------------

static inline size_t align_up(size_t x, size_t a) { return (x + a - 1) & ~(a - 1); }

extern "C" void kernel_launch(void* const* d_in, const int* in_sizes, int n_in,
                              void* d_out, int out_size, void* d_ws, size_t ws_size,
                              hipStream_t stream) {
    const float* x    = (const float*)d_in[0];   // [N_NODES, N_GENES]
    const int*   eidx = (const int*)d_in[1];     // [2, N_EDGES]: row0 = dst, row1 = src
    const float* ew   = (const float*)d_in[2];   // [N_EDGES]
    float*       out  = (float*)d_out;

    const int* dst = eidx;
    const int* src = eidx + N_EDGES;

    // workspace layout
    char* ws = (char*)d_ws;
    size_t off = 0;
    float* hbuf    = (float*)(ws + off); off += align_up((size_t)N_NODES * N_GENES * 4, 256);
    int*   ssrc    = (int*)  (ws + off); off += align_up((size_t)N_EDGES * 4, 256);
    float* swt     = (float*)(ws + off); off += align_up((size_t)N_EDGES * 4, 256);
    int*   counts  = (int*)  (ws + off); off += align_up((size_t)N_NODES * 4, 256);
    int*   offsets = (int*)  (ws + off); off += align_up((size_t)(N_NODES + 1) * 4, 256);
    int*   cursor  = (int*)  (ws + off); off += align_up((size_t)N_NODES * 4, 256);
    (void)ws_size;

    // ---- build CSR by destination (same work every call) ----
    hipMemsetAsync(counts, 0, (size_t)N_NODES * 4, stream);
    hist_kernel<<<(N_EDGES + 255) / 256, 256, 0, stream>>>(dst, counts);
    exscan_kernel<<<1, 1024, 0, stream>>>(counts, offsets, cursor);
    scatter_kernel<<<(N_EDGES + 255) / 256, 256, 0, stream>>>(dst, src, ew, cursor, ssrc, swt);

    // ---- 10 propagation iterations, ping-pong hbuf <-> d_out ----
    const int waves_per_block = 4;                       // 256 threads
    const int grid = (N_NODES + waves_per_block - 1) / waves_per_block;
    const float* hin = x;
    for (int it = 0; it < NUM_ITERS; ++it) {
        float* hout = (it & 1) ? out : hbuf;             // it=9 (last) -> out
        prop_kernel<<<grid, 256, 0, stream>>>(hin, x, offsets, ssrc, swt, hout);
        hin = hout;
    }
}

// Round 2
// 1403.986 us; speedup vs baseline: 1.0426x; 1.0426x over previous
//
#include <hip/hip_runtime.h>

#define N_NODES 50000
#define N_GENES 256
#define N_EDGES 800000
#define NUM_ITERS 10
#define SCAN_BLK 1024
#define N_SCAN_BLKS ((N_NODES + SCAN_BLK - 1) / SCAN_BLK)   // 49

// ---------------- CSR build (once per launch; cheap vs 10 SpMM passes) ----

__global__ void hist_kernel(const int* __restrict__ dst, int* __restrict__ counts) {
    int e = blockIdx.x * blockDim.x + threadIdx.x;
    if (e < N_EDGES) atomicAdd(&counts[dst[e]], 1);
}

// scan1: per-block (1024 elems) exclusive scan via wave shfl; write block sums.
__global__ __launch_bounds__(SCAN_BLK) void scan1_kernel(
        const int* __restrict__ counts, int* __restrict__ offs,
        int* __restrict__ bsums) {
    int i = blockIdx.x * SCAN_BLK + threadIdx.x;
    int lane = threadIdx.x & 63, wid = threadIdx.x >> 6;
    int v = (i < N_NODES) ? counts[i] : 0;
    int x = v;
    #pragma unroll
    for (int o = 1; o < 64; o <<= 1) {
        int t = __shfl_up(x, o, 64);
        if (lane >= o) x += t;
    }
    __shared__ int wsum[16];
    if (lane == 63) wsum[wid] = x;
    __syncthreads();
    if (wid == 0 && lane < 16) {
        int y = wsum[lane];
        #pragma unroll
        for (int o = 1; o < 16; o <<= 1) {
            int t = __shfl_up(y, o, 64);
            if (lane >= o) y += t;
        }
        wsum[lane] = y;
    }
    __syncthreads();
    int pref = (wid > 0) ? wsum[wid - 1] : 0;
    int incl = x + pref;
    if (i < N_NODES) offs[i] = incl - v;               // block-local exclusive
    if (threadIdx.x == SCAN_BLK - 1) bsums[blockIdx.x] = incl;  // block total
}

// scan2: one wave scans the 49 block sums.
__global__ void scan2_kernel(const int* __restrict__ bsums,
                             int* __restrict__ bpref,
                             int* __restrict__ offs_total) {
    int lane = threadIdx.x;  // 64 threads
    int v = (lane < N_SCAN_BLKS) ? bsums[lane] : 0;
    int x = v;
    #pragma unroll
    for (int o = 1; o < 64; o <<= 1) {
        int t = __shfl_up(x, o, 64);
        if (lane >= o) x += t;
    }
    if (lane < N_SCAN_BLKS) bpref[lane] = x - v;
    if (lane == 63) offs_total[0] = x;   // == N_EDGES -> offsets[N_NODES]
}

// scan3: add block prefix; init cursor.
__global__ __launch_bounds__(SCAN_BLK) void scan3_kernel(
        int* __restrict__ offs, const int* __restrict__ bpref,
        int* __restrict__ cursor) {
    int i = blockIdx.x * SCAN_BLK + threadIdx.x;
    if (i < N_NODES) {
        int o = offs[i] + bpref[blockIdx.x];
        offs[i] = o;
        cursor[i] = o;
    }
}

// scatter: interleaved (src, w) pairs so prop does one 8B load per edge slot.
__global__ void scatter_kernel(const int* __restrict__ dst,
                               const int* __restrict__ src,
                               const float* __restrict__ w,
                               int* __restrict__ cursor,
                               int2* __restrict__ edges) {
    int e = blockIdx.x * blockDim.x + threadIdx.x;
    if (e < N_EDGES) {
        int d = dst[e];
        int p = atomicAdd(&cursor[d], 1);
        edges[p] = make_int2(src[e], __float_as_int(w[e]));
    }
}

// ---------------- Propagation: one wave per destination node --------------
// Wave loads its whole edge list lane-parallel (64 edges per 8B load), then
// broadcasts (src,w) via shfl -- no per-edge VMEM pointer-chase. 8 h-row
// gathers (1KB each, fully coalesced) kept in flight per wave.

__global__ __launch_bounds__(256) void prop_kernel(
        const float* __restrict__ h,
        const float* __restrict__ orig,
        const int* __restrict__ offsets,
        const int2* __restrict__ edges,
        float* __restrict__ out) {
    int node = blockIdx.x * 4 + (threadIdx.x >> 6);
    if (node >= N_NODES) return;
    int lane = threadIdx.x & 63;
    int lane4 = lane << 2;

    int beg = offsets[node];
    int end = offsets[node + 1];

    float4 acc = make_float4(0.f, 0.f, 0.f, 0.f);

    for (int base = beg; base < end; base += 64) {
        int cnt = end - base;
        if (cnt > 64) cnt = 64;
        int2 el = make_int2(0, 0);
        if (lane < cnt) el = edges[base + lane];

        int k = 0;
        for (; k + 8 <= cnt; k += 8) {
            int   s0 = __shfl(el.x, k + 0), s1 = __shfl(el.x, k + 1);
            int   s2 = __shfl(el.x, k + 2), s3 = __shfl(el.x, k + 3);
            int   s4 = __shfl(el.x, k + 4), s5 = __shfl(el.x, k + 5);
            int   s6 = __shfl(el.x, k + 6), s7 = __shfl(el.x, k + 7);
            float w0 = __int_as_float(__shfl(el.y, k + 0));
            float w1 = __int_as_float(__shfl(el.y, k + 1));
            float w2 = __int_as_float(__shfl(el.y, k + 2));
            float w3 = __int_as_float(__shfl(el.y, k + 3));
            float w4 = __int_as_float(__shfl(el.y, k + 4));
            float w5 = __int_as_float(__shfl(el.y, k + 5));
            float w6 = __int_as_float(__shfl(el.y, k + 6));
            float w7 = __int_as_float(__shfl(el.y, k + 7));
            float4 r0 = *reinterpret_cast<const float4*>(&h[(size_t)s0 * N_GENES + lane4]);
            float4 r1 = *reinterpret_cast<const float4*>(&h[(size_t)s1 * N_GENES + lane4]);
            float4 r2 = *reinterpret_cast<const float4*>(&h[(size_t)s2 * N_GENES + lane4]);
            float4 r3 = *reinterpret_cast<const float4*>(&h[(size_t)s3 * N_GENES + lane4]);
            float4 r4 = *reinterpret_cast<const float4*>(&h[(size_t)s4 * N_GENES + lane4]);
            float4 r5 = *reinterpret_cast<const float4*>(&h[(size_t)s5 * N_GENES + lane4]);
            float4 r6 = *reinterpret_cast<const float4*>(&h[(size_t)s6 * N_GENES + lane4]);
            float4 r7 = *reinterpret_cast<const float4*>(&h[(size_t)s7 * N_GENES + lane4]);
            acc.x += w0 * r0.x + w1 * r1.x + w2 * r2.x + w3 * r3.x
                   + w4 * r4.x + w5 * r5.x + w6 * r6.x + w7 * r7.x;
            acc.y += w0 * r0.y + w1 * r1.y + w2 * r2.y + w3 * r3.y
                   + w4 * r4.y + w5 * r5.y + w6 * r6.y + w7 * r7.y;
            acc.z += w0 * r0.z + w1 * r1.z + w2 * r2.z + w3 * r3.z
                   + w4 * r4.z + w5 * r5.z + w6 * r6.z + w7 * r7.z;
            acc.w += w0 * r0.w + w1 * r1.w + w2 * r2.w + w3 * r3.w
                   + w4 * r4.w + w5 * r5.w + w6 * r6.w + w7 * r7.w;
        }
        for (; k < cnt; ++k) {
            int   s = __shfl(el.x, k);
            float w = __int_as_float(__shfl(el.y, k));
            float4 r = *reinterpret_cast<const float4*>(&h[(size_t)s * N_GENES + lane4]);
            acc.x += w * r.x;
            acc.y += w * r.y;
            acc.z += w * r.z;
            acc.w += w * r.w;
        }
    }

    size_t idx = (size_t)node * N_GENES + lane4;
    float4 o = *reinterpret_cast<const float4*>(&orig[idx]);
    float4 r;
    r.x = (o.x != 0.f) ? o.x : acc.x;
    r.y = (o.y != 0.f) ? o.y : acc.y;
    r.z = (o.z != 0.f) ? o.z : acc.z;
    r.w = (o.w != 0.f) ? o.w : acc.w;
    *reinterpret_cast<float4*>(&out[idx]) = r;
}

// --------------------------------------------------------------------------

static inline size_t align_up(size_t x, size_t a) { return (x + a - 1) & ~(a - 1); }

extern "C" void kernel_launch(void* const* d_in, const int* in_sizes, int n_in,
                              void* d_out, int out_size, void* d_ws, size_t ws_size,
                              hipStream_t stream) {
    const float* x    = (const float*)d_in[0];   // [N_NODES, N_GENES]
    const int*   eidx = (const int*)d_in[1];     // [2, N_EDGES]: row0 = dst, row1 = src
    const float* ew   = (const float*)d_in[2];   // [N_EDGES]
    float*       out  = (float*)d_out;

    const int* dst = eidx;
    const int* src = eidx + N_EDGES;

    // workspace layout
    char* ws = (char*)d_ws;
    size_t off = 0;
    float* hbuf    = (float*)(ws + off); off += align_up((size_t)N_NODES * N_GENES * 4, 256);
    int2*  edges   = (int2*) (ws + off); off += align_up((size_t)N_EDGES * 8, 256);
    int*   counts  = (int*)  (ws + off); off += align_up((size_t)N_NODES * 4, 256);
    int*   offsets = (int*)  (ws + off); off += align_up((size_t)(N_NODES + 1) * 4, 256);
    int*   cursor  = (int*)  (ws + off); off += align_up((size_t)N_NODES * 4, 256);
    int*   bsums   = (int*)  (ws + off); off += align_up((size_t)N_SCAN_BLKS * 4, 256);
    int*   bpref   = (int*)  (ws + off); off += align_up((size_t)N_SCAN_BLKS * 4, 256);
    (void)ws_size;

    // ---- build CSR by destination ----
    hipMemsetAsync(counts, 0, (size_t)N_NODES * 4, stream);
    hist_kernel<<<(N_EDGES + 255) / 256, 256, 0, stream>>>(dst, counts);
    scan1_kernel<<<N_SCAN_BLKS, SCAN_BLK, 0, stream>>>(counts, offsets, bsums);
    scan2_kernel<<<1, 64, 0, stream>>>(bsums, bpref, &offsets[N_NODES]);
    scan3_kernel<<<N_SCAN_BLKS, SCAN_BLK, 0, stream>>>(offsets, bpref, cursor);
    scatter_kernel<<<(N_EDGES + 255) / 256, 256, 0, stream>>>(dst, src, ew, cursor, edges);

    // ---- 10 propagation iterations, ping-pong hbuf <-> d_out ----
    const int grid = (N_NODES + 3) / 4;              // 4 waves (nodes) per block
    const float* hin = x;
    for (int it = 0; it < NUM_ITERS; ++it) {
        float* hout = (it & 1) ? out : hbuf;         // it=9 (last) -> out
        prop_kernel<<<grid, 256, 0, stream>>>(hin, x, offsets, edges, hout);
        hin = hout;
    }
}